// Round 5
// baseline (1006.932 us; speedup 1.0000x reference)
//
#include <hip/hip_runtime.h>

#define BB 256
#define TT 1024
#define KK 64

// ---------------------------------------------------------------------------
// Grid: 512 blocks x 128 threads.
//  blocks [0,256):   forward logsumexp. wave0 = barrier-free single-wave
//                    recurrence (lane=state j); wave1 = path score gathers.
//  blocks [256,512): Viterbi. wave0 = barrier-free single-wave recurrence
//                    writing bpl to LDS; then ONE barrier; 128-thread
//                    compose + backtrace epilogue.
// Key idea: no __syncthreads in the 1023-step loops -> no vmcnt(0) barrier
// drain -> global emission prefetch ring stays in flight.
// ---------------------------------------------------------------------------
__global__ __launch_bounds__(128) void crf_mega_kernel(
    const float* __restrict__ em, const int* __restrict__ mask,
    const float* __restrict__ trans, const int* __restrict__ tags,
    float* __restrict__ out_dec, float* ll_sum, int* match, int* maskSum) {

  __shared__ float sd[2][KK];               // s (fwd, exp-domain) or delta
  __shared__ unsigned char bpl[TT][KK];     // viterbi backpointers (64 KB)
  __shared__ unsigned char mrow[TT];        // mask row as u8
  __shared__ unsigned char segm[32][KK];    // composed 32-step maps
  __shared__ unsigned char bs[40];          // boundary states
  __shared__ int redm[32];

  const int role = (blockIdx.x >= BB) ? 1 : 0;
  const int b = blockIdx.x & (BB - 1);
  const int tid = threadIdx.x;
  const int wv = tid >> 6;
  const int l = tid & 63;

  const float* emb = em + (size_t)b * TT * KK;
  const int* mb = mask + (size_t)b * TT;
  const int* tgb = tags + (size_t)b * TT;

  if (role == 0) {
    // =========================== FORWARD ===========================
    if (wv == 0) {
      const int j = l;
      // mask row into LDS (wave-local use only)
      for (int t = l; t < TT; t += 64) mrow[t] = (unsigned char)(mb[t] ? 1 : 0);
      float E[KK];
#pragma unroll
      for (int r = 0; r < KK; ++r) E[r] = __expf(trans[r * KK + j]);

      // init: raw e0 -> LDS, global max, s = exp(e0 - m0) into sd[1]
      float e0 = emb[j];
      sd[0][j] = e0;
      float a0[16];
      {
        const float4* rv = reinterpret_cast<const float4*>(&sd[0][0]);
#pragma unroll
        for (int k = 0; k < 16; k += 4) {
          float4 x0 = rv[k], x1 = rv[k+1], x2 = rv[k+2], x3 = rv[k+3];
          a0[k]   = fmaxf(fmaxf(x0.x, x0.y), fmaxf(x0.z, x0.w));
          a0[k+1] = fmaxf(fmaxf(x1.x, x1.y), fmaxf(x1.z, x1.w));
          a0[k+2] = fmaxf(fmaxf(x2.x, x2.y), fmaxf(x2.z, x2.w));
          a0[k+3] = fmaxf(fmaxf(x3.x, x3.y), fmaxf(x3.z, x3.w));
        }
      }
      float m0 = a0[0];
#pragma unroll
      for (int k = 1; k < 16; ++k) m0 = fmaxf(m0, a0[k]);
      sd[1][j] = __expf(e0 - m0);
      float offset = m0;

      float ep[8];
#pragma unroll
      for (int k = 0; k < 8; ++k) ep[k] = emb[(size_t)(1 + k) * KK + j];

      auto fwd_body = [&](int t, float e) {
        int p = t & 1, pn = p ^ 1;
        const float4* sv = reinterpret_cast<const float4*>(&sd[p][0]);
        float4 a[16];
#pragma unroll
        for (int k = 0; k < 16; ++k) a[k] = sv[k];
        float sown = sd[p][j];
        float4 ac0 = {0,0,0,0}, ac1 = {0,0,0,0}, ac2 = {0,0,0,0}, ac3 = {0,0,0,0};
#pragma unroll
        for (int k = 0; k < 4; ++k) {
          const float4 ea0 = {E[16*k+0],E[16*k+1],E[16*k+2],E[16*k+3]};
          const float4 ea1 = {E[16*k+4],E[16*k+5],E[16*k+6],E[16*k+7]};
          const float4 ea2 = {E[16*k+8],E[16*k+9],E[16*k+10],E[16*k+11]};
          const float4 ea3 = {E[16*k+12],E[16*k+13],E[16*k+14],E[16*k+15]};
          ac0.x += a[4*k].x*ea0.x;   ac0.y += a[4*k].y*ea0.y;
          ac0.z += a[4*k].z*ea0.z;   ac0.w += a[4*k].w*ea0.w;
          ac1.x += a[4*k+1].x*ea1.x; ac1.y += a[4*k+1].y*ea1.y;
          ac1.z += a[4*k+1].z*ea1.z; ac1.w += a[4*k+1].w*ea1.w;
          ac2.x += a[4*k+2].x*ea2.x; ac2.y += a[4*k+2].y*ea2.y;
          ac2.z += a[4*k+2].z*ea2.z; ac2.w += a[4*k+2].w*ea2.w;
          ac3.x += a[4*k+3].x*ea3.x; ac3.y += a[4*k+3].y*ea3.y;
          ac3.z += a[4*k+3].z*ea3.z; ac3.w += a[4*k+3].w*ea3.w;
        }
        float q = ((ac0.x+ac0.y)+(ac0.z+ac0.w)) + ((ac1.x+ac1.y)+(ac1.z+ac1.w))
                + ((ac2.x+ac2.y)+(ac2.z+ac2.w)) + ((ac3.x+ac3.y)+(ac3.z+ac3.w));
        q *= __expf(e);
        q = mrow[t] ? q : sown;
        if ((t & 7) == 0) {  // renorm from pre-update s (identical on all lanes)
          float gm = fmaxf(fmaxf(a[0].x, a[0].y), fmaxf(a[0].z, a[0].w));
#pragma unroll
          for (int k = 1; k < 16; ++k)
            gm = fmaxf(gm, fmaxf(fmaxf(a[k].x, a[k].y), fmaxf(a[k].z, a[k].w)));
          q *= __builtin_amdgcn_rcpf(gm);
          offset += __logf(gm);
        }
        sd[pn][j] = q;
      };

      for (int tb = 1; tb + 7 <= TT - 1; tb += 8) {
#pragma unroll
        for (int k = 0; k < 8; ++k) {
          int t = tb + k;
          float e = ep[k];
          int tpre = t + 8; if (tpre > TT - 1) tpre = TT - 1;
          ep[k] = emb[(size_t)tpre * KK + j];
          fwd_body(t, e);
        }
      }
#pragma unroll
      for (int k = 0; k < 7; ++k) fwd_body(1017 + k, ep[k]);  // t=1017..1023

      // final s in sd[0]; all lanes compute, lane 0 commits
      float ssum = 0.f;
      {
        const float4* sv = reinterpret_cast<const float4*>(&sd[0][0]);
#pragma unroll
        for (int k = 0; k < 16; ++k) {
          float4 x = sv[k];
          ssum += (x.x + x.y) + (x.z + x.w);
        }
      }
      if (l == 0) atomicAdd(ll_sum, -(offset + __logf(ssum)));
    } else {
      // ------------------ path score (wave 1) ------------------
      float acc = 0.f;
      int cnt = 0;
      for (int t = l; t < TT; t += 64) {
        if (mb[t]) {
          int tg = tgb[t];
          acc += emb[(size_t)t * KK + tg];
          cnt += 1;
          if (t >= 1) acc += trans[tgb[t - 1] * KK + tg];
        }
      }
#pragma unroll
      for (int off = 1; off <= 32; off <<= 1) {
        acc += __shfl_xor(acc, off);
        cnt += __shfl_xor(cnt, off);
      }
      if (l == 0) { atomicAdd(ll_sum, acc); atomicAdd(maskSum, cnt); }
    }
  } else {
    // =========================== VITERBI ===========================
    if (wv == 0) {
      const int j = l;
      for (int t = l; t < TT; t += 64) mrow[t] = (unsigned char)(mb[t] ? 1 : 0);
      float C[KK];
#pragma unroll
      for (int r = 0; r < KK; ++r) C[r] = trans[r * KK + j];

      sd[1][j] = emb[j];  // delta0

      float ep[8];
#pragma unroll
      for (int k = 0; k < 8; ++k) ep[k] = emb[(size_t)(1 + k) * KK + j];

      auto vit_body = [&](int t, float e) {
        int p = t & 1, pn = p ^ 1;
        const float4* dv = reinterpret_cast<const float4*>(&sd[p][0]);
        float v[KK];
#pragma unroll
        for (int k = 0; k < 16; ++k) {
          float4 x = dv[k];
          v[4*k]   = x.x + C[4*k];
          v[4*k+1] = x.y + C[4*k+1];
          v[4*k+2] = x.z + C[4*k+2];
          v[4*k+3] = x.w + C[4*k+3];
        }
        float down = sd[p][j];
        // per-quarter value max (exact; max is associative) + descending
        // equality scan -> lowest index on ties (== numpy first-occurrence)
        float bq[4]; int iq[4];
#pragma unroll
        for (int qd = 0; qd < 4; ++qd) {
          const int base = 16 * qd;
          float m01 = v[base];
#pragma unroll
          for (int r = 1; r < 16; ++r) m01 = fmaxf(m01, v[base + r]);
          int ii = base + 15;
#pragma unroll
          for (int r = 14; r >= 0; --r)
            ii = (v[base + r] == m01) ? (base + r) : ii;
          bq[qd] = m01; iq[qd] = ii;
        }
        float best = fmaxf(fmaxf(bq[0], bq[1]), fmaxf(bq[2], bq[3]));
        int bidx = iq[3];
        bidx = (bq[2] == best) ? iq[2] : bidx;
        bidx = (bq[1] == best) ? iq[1] : bidx;
        bidx = (bq[0] == best) ? iq[0] : bidx;
        int m = mrow[t];
        float nd = m ? (best + e) : down;
        int bp = m ? bidx : j;
        sd[pn][j] = nd;
        bpl[t][j] = (unsigned char)bp;
      };

      for (int tb = 1; tb + 7 <= TT - 1; tb += 8) {
#pragma unroll
        for (int k = 0; k < 8; ++k) {
          int t = tb + k;
          float e = ep[k];
          int tpre = t + 8; if (tpre > TT - 1) tpre = TT - 1;
          ep[k] = emb[(size_t)tpre * KK + j];
          vit_body(t, e);
        }
      }
#pragma unroll
      for (int k = 0; k < 7; ++k) vit_body(1017 + k, ep[k]);  // t=1017..1023
    }
    __syncthreads();  // ONE barrier: bpl/mrow/sd ready for the epilogue

    // ---- compose 32-step segment maps: 2048 chains, 16 per thread ----
    {
      int j0 = tid & 63;
      int sh = tid >> 6;  // 0..1 ; chains s = sh + 2*kk
      int xs[16];
      int tEnd[16], tStart[16];
#pragma unroll
      for (int kk = 0; kk < 16; ++kk) {
        int s = sh + 2 * kk;
        xs[kk] = j0;
        tStart[kk] = 32 * s + 1;
        tEnd[kk] = (s == 31) ? (TT - 1) : (32 * s + 32);
      }
      for (int q = 0; q < 32; ++q) {
#pragma unroll
        for (int kk = 0; kk < 16; ++kk) {
          int t = tEnd[kk] - q;
          if (t >= tStart[kk]) xs[kk] = bpl[t][xs[kk]];
        }
      }
#pragma unroll
      for (int kk = 0; kk < 16; ++kk)
        segm[sh + 2 * kk][j0] = (unsigned char)xs[kk];
    }
    __syncthreads();

    if (tid == 0) {  // last_tag argmax (delta in sd[0]) + boundary walk
      float bd = sd[0][0];
      int lt = 0;
      for (int i = 1; i < KK; ++i) {
        float v2 = sd[0][i];
        if (v2 > bd) { bd = v2; lt = i; }
      }
      bs[32] = (unsigned char)lt;
      for (int s = 31; s >= 0; --s) bs[s] = segm[s][bs[s + 1]];
    }
    __syncthreads();

    if (tid < 32) {  // per-segment backtrace
      int s = tid;
      int x = bs[s + 1];
      int cnt = 0;
      int tEnd = (s == 31) ? (TT - 1) : (32 * s + 32);
      if (s == 31) {
        int m = mrow[TT - 1];
        out_dec[(size_t)b * TT + TT - 1] = (float)(m ? x : 0);
        cnt += (m && x == tgb[TT - 1]);
      }
      for (int t = tEnd; t >= 32 * s + 1; --t) {
        x = bpl[t][x];
        int m2 = mrow[t - 1];
        out_dec[(size_t)b * TT + t - 1] = (float)(m2 ? x : 0);
        cnt += (m2 && x == tgb[t - 1]);
      }
      redm[s] = cnt;
    }
    __syncthreads();
    if (tid == 0) {
      int c = 0;
      for (int s = 0; s < 32; ++s) c += redm[s];
      atomicAdd(match, c);
    }
  }
}

__global__ void finalize_kernel(const float* ll_sum, const int* match,
                                const int* maskSum, float* d_out) {
  d_out[0] = -(*ll_sum) / (float)BB;
  d_out[1 + BB * TT] = (float)(*match) / (float)(*maskSum);
}

extern "C" void kernel_launch(void* const* d_in, const int* in_sizes, int n_in,
                              void* d_out, int out_size, void* d_ws, size_t ws_size,
                              hipStream_t stream) {
  const float* em = (const float*)d_in[0];
  const int* tags = (const int*)d_in[1];
  const int* mask = (const int*)d_in[2];       // bool -> int32 on device
  const float* trans = (const float*)d_in[3];
  float* out = (float*)d_out;

  float* ll_sum = (float*)d_ws;
  int* match = (int*)((char*)d_ws + 4);
  int* maskSum = (int*)((char*)d_ws + 8);

  hipMemsetAsync(d_ws, 0, 12, stream);
  crf_mega_kernel<<<2 * BB, 128, 0, stream>>>(em, mask, trans, tags, out + 1,
                                              ll_sum, match, maskSum);
  finalize_kernel<<<1, 1, 0, stream>>>(ll_sum, match, maskSum, out);
}